// Round 8
// baseline (204.536 us; speedup 1.0000x reference)
//
#include <hip/hip_runtime.h>
#include <math.h>

#define S_LEN 262144
#define N 128
#define TPB 128
#define GRID 768
#define NWAVES (GRID * 2)          // 1536 waves (2 per block), 3 blocks/CU resident
#define ITEMS (S_LEN / 16 * 2)     // strip(16 rows) x col-half = 32768 items
#define DEPTH 3                    // LDS ring depth per wave (2 items prefetch ahead)
#define STRIP_B 8192               // 16 rows x 128 fp32
#define BUF_B 8704                 // + 512 B boundary row
// 10 DMA issues per item -> steady-state wait allows 2 bufs (20) outstanding
#define VMCNT_WAIT "s_waitcnt vmcnt(20)"

typedef __attribute__((ext_vector_type(8))) short bf16x8;
typedef __attribute__((ext_vector_type(4))) float f32x4;
typedef __attribute__((ext_vector_type(4))) unsigned u32x4;

__device__ __forceinline__ unsigned short f2bf(float x) {
    unsigned b = __float_as_uint(x);
    b = (b + 0x7FFF + ((b >> 16) & 1)) >> 16;   // RNE to bf16
    return (unsigned short)b;
}
// low16 = bf16(x), high16 = bf16(y) (round-half-up): 2 adds + 1 perm
__device__ __forceinline__ unsigned pack2bf(float x, float y) {
    return __builtin_amdgcn_perm(__float_as_uint(y) + 0x8000u,
                                 __float_as_uint(x) + 0x8000u, 0x07060302u);
}
__device__ __forceinline__ float wave_reduce(float v) {
    #pragma unroll
    for (int off = 32; off > 0; off >>= 1) v += __shfl_down(v, off, 64);
    return v;
}
__device__ __forceinline__ void lds_fence() {
    asm volatile("s_waitcnt lgkmcnt(0)" ::: "memory");
}
// async global->LDS DMA: dest = uniform base + lane*size, source per-lane
__device__ __forceinline__ void gload_lds16(const void* g, void* l) {
    __builtin_amdgcn_global_load_lds(
        (const __attribute__((address_space(1))) unsigned int*)g,
        (__attribute__((address_space(3))) unsigned int*)l, 16, 0, 0);
}
__device__ __forceinline__ void gload_lds4(const void* g, void* l) {
    __builtin_amdgcn_global_load_lds(
        (const __attribute__((address_space(1))) unsigned int*)g,
        (__attribute__((address_space(3))) unsigned int*)l, 4, 0, 0);
}

// M = W_K^T @ W_Q (128x128) fp32; emit bf16 in MFMA-B-fragment order.
// l1 partials -> wsP[block]; out[0] zeroed here (kernel-boundary ordering).
__global__ void mk_kernel(const float* __restrict__ WQ, const float* __restrict__ WK,
                          unsigned short* __restrict__ fragB, float* __restrict__ wsP,
                          float* __restrict__ out) {
    const int i = blockIdx.x;
    const int j = threadIdx.x;
    float a0 = 0.f, a1 = 0.f, a2 = 0.f, a3 = 0.f;
    #pragma unroll
    for (int r = 0; r < N; r += 4) {
        a0 = fmaf(WK[(r + 0) * N + i], WQ[(r + 0) * N + j], a0);
        a1 = fmaf(WK[(r + 1) * N + i], WQ[(r + 1) * N + j], a1);
        a2 = fmaf(WK[(r + 2) * N + i], WQ[(r + 2) * N + j], a2);
        a3 = fmaf(WK[(r + 3) * N + i], WQ[(r + 3) * N + j], a3);
    }
    const float acc = (a0 + a1) + (a2 + a3);

    const int kk = i >> 5, q = (i >> 3) & 3, jj = i & 7;
    const int ct = j >> 4, n15 = j & 15;
    fragB[((kk * 8 + ct) * 64 + (q * 16 + n15)) * 8 + jj] = f2bf(acc);

    float sg = fabsf(1.0f / (1.0f + __expf(-acc)));
    float ws = wave_reduce(sg);
    __shared__ float red[2];
    if ((j & 63) == 0) red[j >> 6] = ws;
    __syncthreads();
    if (j == 0) wsP[i] = red[0] + red[1];
    if (i == 0 && j == 0) out[0] = 0.f;
}

// 10 DMA issues for item 'it' into per-wave buffer 'BB':
//   8 x w16: strip rows 0-15 fp32, source XOR-swizzled so LDS chunk (row,c)
//            holds global chunk (row, c^(row&7))  [conflict-free swizzled reads]
//   2 x w4:  boundary row (r0+16) fp32, linear at STRIP_B, exact 512 B
#define DMA_ITEM(it, BB) do {                                                   \
    const long _r0 = (long)((it) >> 1) * 16;                                    \
    const char* _gb = (const char*)In + _r0 * 512;                              \
    _Pragma("unroll")                                                           \
    for (int _j = 0; _j < 8; ++_j)                                              \
        gload_lds16(_gb + gofs[_j], (char*)(BB) + _j * 1024);                   \
    long _rX = _r0 + 16; if (_rX > S_LEN - 1) _rX = S_LEN - 1;                  \
    const float* _bx = In + _rX * N;                                            \
    gload_lds4(_bx + lane,      (char*)(BB) + STRIP_B);                         \
    gload_lds4(_bx + 64 + lane, (char*)(BB) + STRIP_B + 256);                   \
} while (0)

// Wave-autonomous DEPTH-3 DMA pipeline: loads stream into the LDS ring with no
// VGPR round-trip; the single counted vmcnt(20) at loop top leaves the next two
// items' 20 DMAs in flight (never drains). Issue->consume = 2 full iterations.
__global__ __launch_bounds__(TPB, 2) void main_kernel(
    const float* __restrict__ In, const unsigned short* __restrict__ fragB,
    const float* __restrict__ wsP, float* __restrict__ out, float inv_denom) {
    __shared__ __align__(16) unsigned char sBuf[2][DEPTH][BUF_B];
    __shared__ float sRed[2];

    const int tid = threadIdx.x;
    const int w = tid >> 6, lane = tid & 63;
    const int q = lane >> 4, n15 = lane & 15, s7 = n15 & 7;
    const int gid = blockIdx.x * 2 + w;          // global wave id
    const int half = gid & 1;                    // col half (item stride is even)

    // per-lane, item-invariant swizzled source offsets (bytes within strip):
    // DMA issue j, lane l -> LDS chunk (row = 2j + (l>>5), c = l&31)
    int gofs[8];
    {
        const int c = lane & 31, rowof = lane >> 5;
        #pragma unroll
        for (int j = 0; j < 8; ++j) {
            const int row = j * 2 + rowof;
            gofs[j] = row * 512 + ((c ^ (row & 7)) << 4);
        }
    }

    // l1 finalize first (its compiler-inserted waits precede all DMA issues)
    if (blockIdx.x == 0 && w == 0) {
        float p = wsP[lane] + wsP[lane + 64];
        float s = wave_reduce(p);
        if (lane == 0) out[1] = s;
    }

    // B fragments for this wave's 64 cols, constant all kernel (16 loads,
    // issued BEFORE the DMAs -> compiler's pre-loop wait for them is vmcnt(30),
    // which leaves all 30 prologue DMAs in flight)
    bf16x8 bF[4][4];
    #pragma unroll
    for (int c4 = 0; c4 < 4; ++c4)
        #pragma unroll
        for (int kk = 0; kk < 4; ++kk)
            bF[c4][kk] = *(const bf16x8*)&fragB[((kk * 8 + (half * 4 + c4)) * 64 + lane) * 8];

    bf16x8 bOne;   // all-ones B: rowsum via MFMA, C/D layout matches epilogue
    #pragma unroll
    for (int e = 0; e < 8; ++e) bOne[e] = (short)0x3F80;

    unsigned char (*bufs)[BUF_B] = sBuf[w];
    // prologue: fill the ring (gid + 2*NWAVES = 4607 < ITEMS, no guards needed)
    DMA_ITEM(gid, bufs[0]);
    DMA_ITEM(gid + NWAVES, bufs[1]);
    DMA_ITEM(gid + 2 * NWAVES, bufs[2]);

    float lsum = 0.f;
    int item = gid, idx = 0;
    while (item < ITEMS) {
        unsigned char* bb = bufs[idx];
        // current buf's 10 DMAs are older than the newest 20 -> landed
        asm volatile(VMCNT_WAIT ::: "memory");

        // fragments from swizzled LDS + MFMA (z: 4 col-tiles, + rowsum), K=128
        f32x4 acc[4], aRS = (f32x4){0.f, 0.f, 0.f, 0.f};
        #pragma unroll
        for (int c4 = 0; c4 < 4; ++c4) acc[c4] = (f32x4){0.f, 0.f, 0.f, 0.f};
        #pragma unroll
        for (int kk = 0; kk < 4; ++kk) {
            const int y0 = ((kk * 8 + q * 2) ^ s7) << 4;
            const float4 f0 = *(const float4*)(bb + n15 * 512 + y0);
            const float4 f1 = *(const float4*)(bb + n15 * 512 + (y0 ^ 16));
            u32x4 u;
            u.x = pack2bf(f0.x, f0.y); u.y = pack2bf(f0.z, f0.w);
            u.z = pack2bf(f1.x, f1.y); u.w = pack2bf(f1.z, f1.w);
            const bf16x8 a = __builtin_bit_cast(bf16x8, u);
            aRS = __builtin_amdgcn_mfma_f32_16x16x32_bf16(a, bOne, aRS, 0, 0, 0);
            #pragma unroll
            for (int c4 = 0; c4 < 4; ++c4)
                acc[c4] = __builtin_amdgcn_mfma_f32_16x16x32_bf16(a, bF[c4][kk], acc[c4], 0, 0, 0);
        }

        // epilogue: C/D row = q*4+reg, col = n15 (per 16-tile); next-row values
        // read as fp32 from the swizzled strip (rows 1-15) or boundary (row 16)
        const long r0 = (long)(item >> 1) * 16;
        #pragma unroll
        for (int reg = 0; reg < 4; ++reg) {
            const int row = q * 4 + reg;
            const float rs = aRS[reg];
            const bool has = (r0 + row < S_LEN - 1);
            const int rr = row + 1;
            #pragma unroll
            for (int c4 = 0; c4 < 4; ++c4) {
                const int col = half * 64 + c4 * 16 + n15;
                const int cc = col >> 2;
                const int offS = rr * 512 + ((cc ^ (rr & 7)) << 4) + ((col & 3) << 2);
                const int offB = STRIP_B + (col << 2);
                const float nxv = *(const float*)(bb + (rr < 16 ? offS : offB));
                const float z = acc[c4][reg];
                const float sp = fmaxf(z, 0.f) + __logf(1.0f + __expf(-fabsf(z)));
                const float o = sp * rs;
                if (has) {
                    const float d = o - nxv;
                    lsum = fmaf(d, d, lsum);
                }
            }
        }

        lds_fence();   // all DS reads of this buf done before DMA refill targets it
        const int nx = item + DEPTH * NWAVES;
        if (nx < ITEMS) DMA_ITEM(nx, bb);

        idx = idx + 1; if (idx == DEPTH) idx = 0;
        item += NWAVES;
    }

    const float wsum = wave_reduce(lsum);
    if ((tid & 63) == 0) sRed[w] = wsum;
    __syncthreads();
    if (tid == 0) atomicAdd(&out[0], (sRed[0] + sRed[1]) * inv_denom);
}

extern "C" void kernel_launch(void* const* d_in, const int* in_sizes, int n_in,
                              void* d_out, int out_size, void* d_ws, size_t ws_size,
                              hipStream_t stream) {
    const float* In = (const float*)d_in[0];
    const float* WQ = (const float*)d_in[1];
    const float* WK = (const float*)d_in[2];
    float* out = (float*)d_out;
    unsigned short* fragB = (unsigned short*)d_ws;          // 32 KB
    float* wsP = (float*)((char*)d_ws + 32 * 1024);         // 128 floats: l1 partials

    mk_kernel<<<128, 128, 0, stream>>>(WQ, WK, fragB, wsP, out);
    const float inv = (float)(1.0 / ((double)(S_LEN - 1) * (double)N));
    main_kernel<<<GRID, TPB, 0, stream>>>(In, fragB, wsP, out, inv);
}